// Round 2
// baseline (767.850 us; speedup 1.0000x reference)
//
#include <hip/hip_runtime.h>

// ChunkedValueCrossAttn: softmax over a singleton context axis == 1.0, so the
// output is y[b,c,h,w] = (Wo @ (Wv @ context[b]))[c] + bo[c] — constant over
// (h,w). x/Wq/Wk never affect the output. Pure 512MB broadcast write.

#define NB 2          // batch
#define QD 64         // output channels (query_dim)
#define CD 16         // context dim
#define ID 32         // inner dim (heads*dim_head)
#define BC_SHIFT 18   // log2(H*W/4) = log2(1024*1024/4)

typedef float vfloat4 __attribute__((ext_vector_type(4)));  // native vector for nontemporal builtin

__global__ __launch_bounds__(256) void cva_broadcast_kernel(
    const float* __restrict__ context,   // [NB, CD]
    const float* __restrict__ Wv,        // [ID, CD]
    const float* __restrict__ Wo,        // [QD, ID]
    const float* __restrict__ bo,        // [QD]
    vfloat4* __restrict__ out,           // [NB*QD*H*W/4]
    int n4)
{
    __shared__ float s_v[NB * ID];
    __shared__ float s_y[NB * QD];

    const int t = threadIdx.x;

    // Step 1: v[b,o] = sum_j context[b,j] * Wv[o,j]   (64 threads)
    if (t < NB * ID) {
        const int b = t / ID, o = t % ID;
        float acc = 0.f;
#pragma unroll
        for (int j = 0; j < CD; ++j)
            acc += context[b * CD + j] * Wv[o * CD + j];
        s_v[t] = acc;
    }
    __syncthreads();

    // Step 2: y[b,c] = bo[c] + sum_o Wo[c,o] * v[b,o]  (128 threads)
    if (t < NB * QD) {
        const int b = t / QD, c = t % QD;
        float acc = bo[c];
#pragma unroll
        for (int o = 0; o < ID; ++o)
            acc += Wo[c * ID + o] * s_v[b * ID + o];
        s_y[t] = acc;
    }
    __syncthreads();

    // Step 3: stream the broadcast out. Each float4 covers 4 consecutive w
    // for a fixed (b,c): bc index = i4 >> 18.
    const int stride = gridDim.x * blockDim.x;
    for (int i = blockIdx.x * blockDim.x + t; i < n4; i += stride) {
        const float val = s_y[i >> BC_SHIFT];
        vfloat4 pkt = { val, val, val, val };
        __builtin_nontemporal_store(pkt, &out[i]);
    }
}

extern "C" void kernel_launch(void* const* d_in, const int* in_sizes, int n_in,
                              void* d_out, int out_size, void* d_ws, size_t ws_size,
                              hipStream_t stream) {
    // inputs: 0=x, 1=context, 2=Wq, 3=Wk, 4=Wv, 5=Wo, 6=bo
    const float* context = (const float*)d_in[1];
    const float* Wv      = (const float*)d_in[4];
    const float* Wo      = (const float*)d_in[5];
    const float* bo      = (const float*)d_in[6];
    vfloat4* out = (vfloat4*)d_out;

    const int n4 = out_size / 4;          // 33,554,432 float4 stores
    const int block = 256;
    const int grid = 8192;                 // grid-stride: 16 f4/thread
    cva_broadcast_kernel<<<grid, block, 0, stream>>>(context, Wv, Wo, bo, out, n4);
}

// Round 3
// 759.874 us; speedup vs baseline: 1.0105x; 1.0105x over previous
//
#include <hip/hip_runtime.h>

// ChunkedValueCrossAttn: softmax over a singleton context axis == 1.0, so the
// output is y[b,c,h,w] = (Wo @ (Wv @ context[b]))[c] + bo[c] — constant over
// (h,w). x/Wq/Wk never affect the output. Pure 512MB broadcast write.
//
// R2 note: nontemporal stores replaced with plain dwordx4 stores — the
// harness's fillBufferAligned hits 6.3 TB/s (79% peak) with plain stores,
// so we mirror that proven pattern.

#define NB 2          // batch
#define QD 64         // output channels (query_dim)
#define CD 16         // context dim
#define ID 32         // inner dim (heads*dim_head)
#define BC_SHIFT 18   // log2(H*W/4) = log2(1024*1024/4)

typedef float vfloat4 __attribute__((ext_vector_type(4)));

__global__ __launch_bounds__(256) void cva_broadcast_kernel(
    const float* __restrict__ context,   // [NB, CD]
    const float* __restrict__ Wv,        // [ID, CD]
    const float* __restrict__ Wo,        // [QD, ID]
    const float* __restrict__ bo,        // [QD]
    vfloat4* __restrict__ out,           // [NB*QD*H*W/4]
    int n4)
{
    __shared__ float s_v[NB * ID];
    __shared__ float s_y[NB * QD];

    const int t = threadIdx.x;

    // Step 1: v[b,o] = sum_j context[b,j] * Wv[o,j]   (64 threads)
    if (t < NB * ID) {
        const int b = t / ID, o = t % ID;
        float acc = 0.f;
#pragma unroll
        for (int j = 0; j < CD; ++j)
            acc += context[b * CD + j] * Wv[o * CD + j];
        s_v[t] = acc;
    }
    __syncthreads();

    // Step 2: y[b,c] = bo[c] + sum_o Wo[c,o] * v[b,o]  (128 threads)
    if (t < NB * QD) {
        const int b = t / QD, c = t % QD;
        float acc = bo[c];
#pragma unroll
        for (int o = 0; o < ID; ++o)
            acc += Wo[c * ID + o] * s_v[b * ID + o];
        s_y[t] = acc;
    }
    __syncthreads();

    // Step 3: stream the broadcast out. Each float4 covers 4 consecutive w
    // for a fixed (b,c): bc index = i4 >> 18. Within a wave the LDS read is
    // (nearly always) uniform -> broadcast, conflict-free.
    const int stride = gridDim.x * blockDim.x;
    for (int i = blockIdx.x * blockDim.x + t; i < n4; i += stride) {
        const float val = s_y[i >> BC_SHIFT];
        vfloat4 pkt = { val, val, val, val };
        out[i] = pkt;
    }
}

extern "C" void kernel_launch(void* const* d_in, const int* in_sizes, int n_in,
                              void* d_out, int out_size, void* d_ws, size_t ws_size,
                              hipStream_t stream) {
    // inputs: 0=x, 1=context, 2=Wq, 3=Wk, 4=Wv, 5=Wo, 6=bo
    const float* context = (const float*)d_in[1];
    const float* Wv      = (const float*)d_in[4];
    const float* Wo      = (const float*)d_in[5];
    const float* bo      = (const float*)d_in[6];
    vfloat4* out = (vfloat4*)d_out;

    const int n4 = out_size / 4;          // 33,554,432 float4 stores
    const int block = 256;
    const int grid = 8192;                 // grid-stride: 16 f4/thread
    cva_broadcast_kernel<<<grid, block, 0, stream>>>(context, Wv, Wo, bo, out, n4);
}